// Round 1
// baseline (268.498 us; speedup 1.0000x reference)
//
#include <hip/hip_runtime.h>
#include <math.h>

#define NLAT 64
#define NLON 128
#define HID  256
#define NSTA 1024
#define NG   (NLAT * NLON)
#define TG   16    // grid points (lons) per block = MFMA M
#define SC   128   // station chunk
#define NCH  4     // chunks per block (half the stations per block now)
#define NGRP 16    // station groups in phase A (256 threads / TG)
#define TABN 2048  // even-symmetric table on [0, TABW)
#define TABW 4.5f

#define LOG2E 1.4426950408889634f
#define LN2   0.69314718055994531f

typedef float f32x4 __attribute__((ext_vector_type(4)));
typedef _Float16 f16x8 __attribute__((ext_vector_type(8)));

// accurate gelu for table build (A&S 7.1.26, |erf err| <= 1.5e-7)
__device__ __forceinline__ float gelu_ref(float x) {
    const float p  = 0.3275911f;
    const float a1 = 0.254829592f, a2 = -0.284496736f, a3 = 1.421413741f,
                a4 = -1.453152027f, a5 = 1.061405429f;
    float z  = x * 0.70710678118654752f;
    float az = fabsf(z);
    float t  = __builtin_amdgcn_rcpf(fmaf(p, az, 1.0f));
    float poly = fmaf(fmaf(fmaf(fmaf(a5, t, a4), t, a3), t, a2), t, a1) * t;
    float e  = __builtin_amdgcn_exp2f(az * az * -LOG2E);
    float r  = fmaf(-poly, e, 1.0f);
    float erfz = copysignf(r, z);
    float hx = 0.5f * x;
    return fmaf(hx, erfz, hx);
}

// ---- Kernel 0: feats [b][s][d] f32 -> F^T hi/lo [b][d][s] f16 (split for precision)
// v2: 32-station tiles so the transposed store is f16x8 (16B, 64B segments per d-row)
__global__ __launch_bounds__(256)
void cvt_kernel(const float* __restrict__ feats, _Float16* __restrict__ fhi,
                _Float16* __restrict__ flo) {
    __shared__ float tile[32][68];         // +4 pad: rows stay 16B aligned, banks spread
    const int blk = blockIdx.x;            // b(2) * st(32) * dt(4) = 256
    const int b  = blk >> 7;
    const int st = (blk >> 2) & 31;
    const int dt = blk & 3;
    {
        const int s  = threadIdx.x >> 3;   // 0..31
        const int dq = threadIdx.x & 7;    // 8 floats each
        const float* src = feats + ((size_t)(b * NSTA + st * 32 + s)) * HID + dt * 64 + dq * 8;
        float4 v0 = *(const float4*)src;
        float4 v1 = *(const float4*)(src + 4);
        *(float4*)&tile[s][dq * 8]     = v0;
        *(float4*)&tile[s][dq * 8 + 4] = v1;
    }
    __syncthreads();
    const int d  = threadIdx.x >> 2;       // 0..63
    const int sq = threadIdx.x & 3;        // 8 stations each
    f16x8 hi8, lo8;
#pragma unroll
    for (int k = 0; k < 8; ++k) {
        float v = tile[sq * 8 + k][d];
        _Float16 h = (_Float16)v;
        hi8[k] = h;
        lo8[k] = (_Float16)(v - (float)h);
    }
    const size_t o = ((size_t)(b * HID + dt * 64 + d)) * NSTA + st * 32 + sq * 8;
    *(f16x8*)&fhi[o] = hi8;
    *(f16x8*)&flo[o] = lo8;
}

// ---- Main kernel: fused score MLP (LUT gelu) + online softmax + MFMA weighted sum.
// Station dim split across 2 blocks (flash-style partials), combined by comb_kernel.
__global__ __launch_bounds__(256, 8)
void s2g_kernel(const float* __restrict__ coords,  // [2][1024][3]
                const float* __restrict__ maskp,   // [2][1024]
                const float* __restrict__ W1,      // [3][32]
                const float* __restrict__ b1,      // [32]
                const float* __restrict__ W2,      // [32]
                const float* __restrict__ b2p,     // [1]
                const _Float16* __restrict__ fhi,  // [2][256][1024]
                const _Float16* __restrict__ flo,  // [2][256][1024]
                float* __restrict__ out,           // [2][256][8192]  (half 0 partial)
                float* __restrict__ acc1,          // [2][256][8192]  (half 1 partial)
                float2* __restrict__ ml)           // [half][b][8192] (m, l)
{
    __shared__ float gtab[TABN];                   // 8 KB: gelu(-x) on [0,4.5) (= gelu-relu, even)
    __shared__ __align__(16) f16x8 fragAh[256];    // 4 KB: P-hi in MFMA A-frag order
    __shared__ __align__(16) f16x8 fragAl[256];    // 4 KB: P-lo
    __shared__ __align__(16) float slat[SC], slon[SC], smask[SC];
    __shared__ float4 wpack[32];                   // (W1row0, W1row1, W1row2, b1) * ISCALE
    __shared__ float2 w2pk[32];                    // (w2, w2/ISCALE)
    __shared__ __align__(16) float redbuf[NGRP * TG]; // union: maxbuf (A->B1) / psum (B2->B3)
    __shared__ __align__(16) float mS[TG], lS[TG], alphaS[TG];

    const int tid  = threadIdx.x;
    const int half = blockIdx.x >> 10;     // station half
    const int b    = (blockIdx.x >> 9) & 1;
    const int blk  = blockIdx.x & 511;     // 64 lat * 8 lon-blocks
    const int lat  = blk >> 3;
    const int lon0 = (blk & 7) * TG;
    const int sbase = half * (NSTA / 2);

    const float latv = -90.0f + (180.0f / 63.0f) * (float)lat;

    const float CELL   = TABW / (float)TABN;       // x units per cell
    const float ISCALE = (float)TABN / TABW;       // cells per x unit

    // even table: gelu(x)-relu(x) = gelu(-|x|); cell k covers [k,k+1) in scaled units
#pragma unroll
    for (int k = tid; k < TABN; k += 256) {
        float x = ((float)k + 0.5f) * CELL;
        gtab[k] = gelu_ref(-x);
    }
    if (tid < 32) {
        // W1, b1 pre-scaled into index space: pre' = pre * ISCALE
        wpack[tid] = make_float4(W1[tid] * ISCALE, W1[32 + tid] * ISCALE,
                                 W1[64 + tid] * ISCALE, b1[tid] * ISCALE);
        w2pk[tid]  = make_float2(W2[tid], W2[tid] * CELL);   // table term, relu term
        if (tid < TG) { mS[tid] = -1.0e30f; lS[tid] = 0.0f; }
    }
    const float b2 = b2p[0];

    // phase A mapping: thread -> (grid col gA, station group sgrp of 8)
    const int gA   = tid & (TG - 1);
    const int sgrp = tid >> 4;             // 0..15
    const float lonvA = -180.0f + (360.0f / 127.0f) * (float)(lon0 + gA);

    // phase C mapping: wave w owns d in [w*64, w*64+64)
    const int lane = tid & 63;
    const int wv   = tid >> 6;

    f32x4 acc[4];
#pragma unroll
    for (int t = 0; t < 4; ++t) acc[t] = (f32x4){0.0f, 0.0f, 0.0f, 0.0f};

    const float* cbase = coords + (size_t)b * NSTA * 3;
    const float* mbase = maskp  + (size_t)b * NSTA;
    const _Float16* fhb = fhi + (size_t)b * HID * NSTA;
    const _Float16* flb = flo + (size_t)b * HID * NSTA;

    for (int c = 0; c < NCH; ++c) {
        const int s0 = sbase + c * SC;
        __syncthreads();   // table/weights visible (c=0); prev MFMA done with frags; redbuf free
        if (tid < SC) {
            slat[tid]  = cbase[(size_t)(s0 + tid) * 3 + 0];
            slon[tid]  = cbase[(size_t)(s0 + tid) * 3 + 1];
            smask[tid] = mbase[s0 + tid];
        }
        __syncthreads();

        // ---- Phase A: scores for 8 stations at grid col gA (LUT gelu, index-space weights)
        float dist[8], dlat[8], dlon[8], v[8];
#pragma unroll
        for (int i = 0; i < 8; ++i) {
            int s = sgrp * 8 + i;
            float dla = slat[s] - latv;
            float dlo = slon[s] - lonvA;
            dlat[i] = dla;
            dlon[i] = dlo;
            dist[i] = sqrtf(fmaf(dla, dla, fmaf(dlo, dlo, 1e-6f)));
            v[i] = b2;
        }
#pragma unroll 2
        for (int j = 0; j < 32; ++j) {
            float4 wj = wpack[j];
            float2 w2 = w2pk[j];
#pragma unroll
            for (int i = 0; i < 8; ++i) {
                float pre = fmaf(wj.x, dist[i], fmaf(wj.y, dlat[i], fmaf(wj.z, dlon[i], wj.w)));
                float a   = fminf(fabsf(pre), (float)TABN - 0.5f);  // abs = free modifier
                int  idx  = (int)a;
                float r   = gtab[idx];                              // ds gather
                v[i] = fmaf(w2.y, fmaxf(pre, 0.0f), v[i]);          // relu part (index units)
                v[i] = fmaf(w2.x, r, v[i]);                         // even table part
            }
        }
        float lmax = -3.0e38f;
#pragma unroll
        for (int i = 0; i < 8; ++i) {
            int s = sgrp * 8 + i;
            float x  = v[i];
            float ax = fabsf(x);
            float e  = __builtin_amdgcn_exp2f(-ax * LOG2E);
            float sp = fmaxf(x, 0.0f) + __builtin_amdgcn_logf(1.0f + e) * LN2;
            v[i] = sp * smask[s];
            lmax = fmaxf(lmax, v[i]);
        }
        redbuf[sgrp * TG + gA] = lmax;
        __syncthreads();

        // ---- B1: running max + rescale factor per grid col
        if (tid < TG) {
            float cm = redbuf[tid];
#pragma unroll
            for (int k = 1; k < NGRP; ++k) cm = fmaxf(cm, redbuf[k * TG + tid]);
            float mold = mS[tid];
            float mnew = fmaxf(mold, cm);
            alphaS[tid] = __builtin_amdgcn_exp2f((mold - mnew) * LOG2E);
            mS[tid] = mnew;
        }
        __syncthreads();

        // ---- B2: p = exp(v-m) -> f16 hi+lo, A-frag layout; sum fp32 p
        {
            float m  = mS[gA];
            float ps = 0.0f;
            f16x8 fh, fl;
#pragma unroll
            for (int i = 0; i < 8; ++i) {
                float p = __builtin_amdgcn_exp2f((v[i] - m) * LOG2E);
                _Float16 h = (_Float16)p;
                fh[i] = h;
                fl[i] = (_Float16)(p - (float)h);
                ps += p;
            }
            const int idx = ((sgrp >> 2) << 6) + (((sgrp & 3) << 4) | gA);
            fragAh[idx] = fh;
            fragAl[idx] = fl;
            redbuf[sgrp * TG + gA] = ps;
        }
        __syncthreads();

        // ---- B3: denominator update (runs alongside phase C)
        if (tid < TG) {
            float t = 0.0f;
#pragma unroll
            for (int k = 0; k < NGRP; ++k) t += redbuf[k * TG + tid];
            lS[tid] = lS[tid] * alphaS[tid] + t;
        }

        // ---- Phase C: rescale accumulators (rows m = (lane>>4)*4+reg), MFMA
        {
            const f32x4 al = *(const f32x4*)&alphaS[(lane >> 4) * 4];
#pragma unroll
            for (int t = 0; t < 4; ++t) acc[t] = acc[t] * al;

            const int srow = s0 + ((lane >> 4) * 8);
            const int dbase = wv * 64 + (lane & 15);
#pragma unroll
            for (int kc = 0; kc < 4; ++kc) {
                f16x8 ah = fragAh[(kc << 6) + lane];
                f16x8 al16 = fragAl[(kc << 6) + lane];
#pragma unroll
                for (int t = 0; t < 4; ++t) {
                    const size_t off = (size_t)(dbase + t * 16) * NSTA + srow + kc * 32;
                    f16x8 bh = *(const f16x8*)(fhb + off);
                    f16x8 bl = *(const f16x8*)(flb + off);
                    acc[t] = __builtin_amdgcn_mfma_f32_16x16x32_f16(ah, bh, acc[t], 0, 0, 0);
                    acc[t] = __builtin_amdgcn_mfma_f32_16x16x32_f16(ah, bl, acc[t], 0, 0, 0);
                    acc[t] = __builtin_amdgcn_mfma_f32_16x16x32_f16(al16, bh, acc[t], 0, 0, 0);
                }
            }
        }
    }
    __syncthreads();   // lS, mS final

    // ---- epilogue: write UNNORMALIZED partial acc + (m,l); comb_kernel merges halves
    {
        float* dst = half ? acc1 : out;
        const int m0 = (lane >> 4) * 4;
        const size_t gbase = (size_t)lat * NLON + lon0 + m0;
#pragma unroll
        for (int t = 0; t < 4; ++t) {
            const int d = wv * 64 + t * 16 + (lane & 15);
            *reinterpret_cast<f32x4*>(dst + ((size_t)(b * HID + d)) * NG + gbase) = acc[t];
        }
        if (tid < TG)
            ml[((half << 1) + b) * NG + lat * NLON + lon0 + tid] = make_float2(mS[tid], lS[tid]);
    }
}

// ---- Combine kernel: out = (acc0*e^{m0-M} + acc1*e^{m1-M}) / (l0*e^{m0-M} + l1*e^{m1-M})
__global__ __launch_bounds__(256)
void comb_kernel(float* __restrict__ out, const float* __restrict__ acc1,
                 const float2* __restrict__ ml) {
    const int x    = blockIdx.x;          // 1024 = b(2) * lat(64) * dseg(8)
    const int b    = x >> 9;
    const int lat  = (x >> 3) & 63;
    const int dseg = x & 7;               // 32 d each
    const int lon  = threadIdx.x & 127;
    const int dsub = threadIdx.x >> 7;    // 0..1
    const int g    = lat * NLON + lon;

    const float2 p0 = ml[b * NG + g];
    const float2 p1 = ml[(2 + b) * NG + g];
    const float M  = fmaxf(p0.x, p1.x);
    float s0 = __builtin_amdgcn_exp2f((p0.x - M) * LOG2E);
    float s1 = __builtin_amdgcn_exp2f((p1.x - M) * LOG2E);
    const float rl = 1.0f / fmaf(p0.y, s0, p1.y * s1);
    s0 *= rl; s1 *= rl;

#pragma unroll 4
    for (int k = 0; k < 16; ++k) {
        const int d = dseg * 32 + dsub + k * 2;
        const size_t o = ((size_t)(b * HID + d)) * NG + g;
        out[o] = fmaf(out[o], s0, acc1[o] * s1);
    }
}

extern "C" void kernel_launch(void* const* d_in, const int* in_sizes, int n_in,
                              void* d_out, int out_size, void* d_ws, size_t ws_size,
                              hipStream_t stream) {
    const float* feats  = (const float*)d_in[0];
    const float* coords = (const float*)d_in[1];
    const float* maskp  = (const float*)d_in[2];
    const float* W1     = (const float*)d_in[3];
    const float* b1     = (const float*)d_in[4];
    const float* W2     = (const float*)d_in[5];
    const float* b2     = (const float*)d_in[6];
    float* out          = (float*)d_out;

    // workspace map:
    //   fhi  [2][256][1024] f16 : 1 MB
    //   flo  [2][256][1024] f16 : 1 MB
    //   acc1 [2][256][8192] f32 : 16 MB   (half-1 partial; half-0 goes to d_out)
    //   ml   [2][2][8192] float2: 256 KB
    _Float16* fhi = (_Float16*)d_ws;
    _Float16* flo = fhi + (size_t)2 * HID * NSTA;
    float*  acc1 = (float*)((char*)d_ws + (size_t)2 * 1048576);
    float2* ml   = (float2*)((char*)d_ws + (size_t)2 * 1048576 + (size_t)2 * HID * NG * 4);

    hipLaunchKernelGGL(cvt_kernel, dim3(256), dim3(256), 0, stream, feats, fhi, flo);
    hipLaunchKernelGGL(s2g_kernel, dim3(2048), dim3(256), 0, stream,
                       coords, maskp, W1, b1, W2, b2, fhi, flo, out, acc1, ml);
    hipLaunchKernelGGL(comb_kernel, dim3(1024), dim3(256), 0, stream, out, acc1, ml);
}

// Round 2
// 255.035 us; speedup vs baseline: 1.0528x; 1.0528x over previous
//
#include <hip/hip_runtime.h>
#include <math.h>

#define NLAT 64
#define NLON 128
#define HID  256
#define NSTA 1024
#define NG   (NLAT * NLON)
#define TG   16    // grid points (lons) per block = MFMA M
#define SC   128   // station chunk
#define NCH  4     // chunks per block (half the stations per block)
#define NGRP 16    // station groups in phase A (256 threads / TG)
#define TABN 2048  // even-symmetric table on [0, TABW)
#define TABW 4.5f

#define LOG2E 1.4426950408889634f
#define LN2   0.69314718055994531f

typedef float f32x4 __attribute__((ext_vector_type(4)));
typedef _Float16 f16x8 __attribute__((ext_vector_type(8)));

// accurate gelu for table build (A&S 7.1.26, |erf err| <= 1.5e-7)
__device__ __forceinline__ float gelu_ref(float x) {
    const float p  = 0.3275911f;
    const float a1 = 0.254829592f, a2 = -0.284496736f, a3 = 1.421413741f,
                a4 = -1.453152027f, a5 = 1.061405429f;
    float z  = x * 0.70710678118654752f;
    float az = fabsf(z);
    float t  = __builtin_amdgcn_rcpf(fmaf(p, az, 1.0f));
    float poly = fmaf(fmaf(fmaf(fmaf(a5, t, a4), t, a3), t, a2), t, a1) * t;
    float e  = __builtin_amdgcn_exp2f(az * az * -LOG2E);
    float r  = fmaf(-poly, e, 1.0f);
    float erfz = copysignf(r, z);
    float hx = 0.5f * x;
    return fmaf(hx, erfz, hx);
}

// ---- Kernel 0: feats [b][s][d] f32 -> F^T hi/lo [b][d][s] f16 (split for precision)
// 32-station tiles so the transposed store is f16x8 (16B, 64B segments per d-row)
__global__ __launch_bounds__(256)
void cvt_kernel(const float* __restrict__ feats, _Float16* __restrict__ fhi,
                _Float16* __restrict__ flo) {
    __shared__ float tile[32][68];         // +4 pad: rows stay 16B aligned, banks spread
    const int blk = blockIdx.x;            // b(2) * st(32) * dt(4) = 256
    const int b  = blk >> 7;
    const int st = (blk >> 2) & 31;
    const int dt = blk & 3;
    {
        const int s  = threadIdx.x >> 3;   // 0..31
        const int dq = threadIdx.x & 7;    // 8 floats each
        const float* src = feats + ((size_t)(b * NSTA + st * 32 + s)) * HID + dt * 64 + dq * 8;
        float4 v0 = *(const float4*)src;
        float4 v1 = *(const float4*)(src + 4);
        *(float4*)&tile[s][dq * 8]     = v0;
        *(float4*)&tile[s][dq * 8 + 4] = v1;
    }
    __syncthreads();
    const int d  = threadIdx.x >> 2;       // 0..63
    const int sq = threadIdx.x & 3;        // 8 stations each
    f16x8 hi8, lo8;
#pragma unroll
    for (int k = 0; k < 8; ++k) {
        float v = tile[sq * 8 + k][d];
        _Float16 h = (_Float16)v;
        hi8[k] = h;
        lo8[k] = (_Float16)(v - (float)h);
    }
    const size_t o = ((size_t)(b * HID + dt * 64 + d)) * NSTA + st * 32 + sq * 8;
    *(f16x8*)&fhi[o] = hi8;
    *(f16x8*)&flo[o] = lo8;
}

// ---- Main kernel: fused score MLP (LUT gelu) + online softmax + MFMA weighted sum.
// Station dim split across 2 blocks (flash-style partials), combined by comb_kernel.
// launch_bounds(256,6): total reg budget 80/wave (unified VGPR+AGPR file).
// acc[4] = 16 AGPRs, so arch-VGPR budget ~64 -> the ~56 arch regs fit WITHOUT
// scratch spills (launch_bounds(256,8) forced arch<=48 -> 70 MB spill traffic).
__global__ __launch_bounds__(256, 6)
void s2g_kernel(const float* __restrict__ coords,  // [2][1024][3]
                const float* __restrict__ maskp,   // [2][1024]
                const float* __restrict__ W1,      // [3][32]
                const float* __restrict__ b1,      // [32]
                const float* __restrict__ W2,      // [32]
                const float* __restrict__ b2p,     // [1]
                const _Float16* __restrict__ fhi,  // [2][256][1024]
                const _Float16* __restrict__ flo,  // [2][256][1024]
                float* __restrict__ out,           // [2][256][8192]  (half 0 partial)
                float* __restrict__ acc1,          // [2][256][8192]  (half 1 partial)
                float2* __restrict__ ml)           // [half][b][8192] (m, l)
{
    __shared__ float gtab[TABN];                   // 8 KB: gelu(-x) on [0,4.5) (= gelu-relu, even)
    __shared__ __align__(16) f16x8 fragAh[256];    // 4 KB: P-hi in MFMA A-frag order
    __shared__ __align__(16) f16x8 fragAl[256];    // 4 KB: P-lo
    __shared__ __align__(16) float slat[SC], slon[SC], smask[SC];
    __shared__ float4 wpack[32];                   // (W1row0, W1row1, W1row2, b1) * ISCALE
    __shared__ float2 w2pk[32];                    // (w2, w2*CELL)
    __shared__ __align__(16) float redbuf[NGRP * TG]; // union: maxbuf (A->B1) / psum (B2->B3)
    __shared__ __align__(16) float mS[TG], lS[TG], alphaS[TG];

    const int tid  = threadIdx.x;
    const int half = blockIdx.x >> 10;     // station half
    const int b    = (blockIdx.x >> 9) & 1;
    const int blk  = blockIdx.x & 511;     // 64 lat * 8 lon-blocks
    const int lat  = blk >> 3;
    const int lon0 = (blk & 7) * TG;
    const int sbase = half * (NSTA / 2);

    const float latv = -90.0f + (180.0f / 63.0f) * (float)lat;

    const float CELL   = TABW / (float)TABN;       // x units per cell
    const float ISCALE = (float)TABN / TABW;       // cells per x unit

    // even table: gelu(x)-relu(x) = gelu(-|x|); cell k covers [k,k+1) in scaled units
#pragma unroll
    for (int k = tid; k < TABN; k += 256) {
        float x = ((float)k + 0.5f) * CELL;
        gtab[k] = gelu_ref(-x);
    }
    if (tid < 32) {
        // W1, b1 pre-scaled into index space: pre' = pre * ISCALE
        wpack[tid] = make_float4(W1[tid] * ISCALE, W1[32 + tid] * ISCALE,
                                 W1[64 + tid] * ISCALE, b1[tid] * ISCALE);
        w2pk[tid]  = make_float2(W2[tid], W2[tid] * CELL);   // table term, relu term
        if (tid < TG) { mS[tid] = -1.0e30f; lS[tid] = 0.0f; }
    }
    const float b2 = b2p[0];

    // phase A mapping: thread -> (grid col gA, station group sgrp of 8)
    const int gA   = tid & (TG - 1);
    const int sgrp = tid >> 4;             // 0..15
    const float lonvA = -180.0f + (360.0f / 127.0f) * (float)(lon0 + gA);

    // phase C mapping: wave w owns d in [w*64, w*64+64)
    const int lane = tid & 63;
    const int wv   = tid >> 6;

    f32x4 acc[4];
#pragma unroll
    for (int t = 0; t < 4; ++t) acc[t] = (f32x4){0.0f, 0.0f, 0.0f, 0.0f};

    const float* cbase = coords + (size_t)b * NSTA * 3;
    const float* mbase = maskp  + (size_t)b * NSTA;
    const _Float16* fhb = fhi + (size_t)b * HID * NSTA;
    const _Float16* flb = flo + (size_t)b * HID * NSTA;

    for (int c = 0; c < NCH; ++c) {
        const int s0 = sbase + c * SC;
        __syncthreads();   // table/weights visible (c=0); prev MFMA done with frags; redbuf free
        if (tid < SC) {
            slat[tid]  = cbase[(size_t)(s0 + tid) * 3 + 0];
            slon[tid]  = cbase[(size_t)(s0 + tid) * 3 + 1];
            smask[tid] = mbase[s0 + tid];
        }
        __syncthreads();

        // ---- Phase A: scores for 8 stations at grid col gA (LUT gelu, index-space weights)
        float dist[8], dlat[8], dlon[8], v[8];
#pragma unroll
        for (int i = 0; i < 8; ++i) {
            int s = sgrp * 8 + i;
            float dla = slat[s] - latv;
            float dlo = slon[s] - lonvA;
            dlat[i] = dla;
            dlon[i] = dlo;
            dist[i] = sqrtf(fmaf(dla, dla, fmaf(dlo, dlo, 1e-6f)));
            v[i] = b2;
        }
#pragma unroll 2
        for (int j = 0; j < 32; ++j) {
            float4 wj = wpack[j];
            float2 w2 = w2pk[j];
#pragma unroll
            for (int i = 0; i < 8; ++i) {
                float pre = fmaf(wj.x, dist[i], fmaf(wj.y, dlat[i], fmaf(wj.z, dlon[i], wj.w)));
                float a   = fminf(fabsf(pre), (float)TABN - 0.5f);  // abs = free modifier
                int  idx  = (int)a;
                float r   = gtab[idx];                              // ds gather
                v[i] = fmaf(w2.y, fmaxf(pre, 0.0f), v[i]);          // relu part (index units)
                v[i] = fmaf(w2.x, r, v[i]);                         // even table part
            }
        }
        float lmax = -3.0e38f;
#pragma unroll
        for (int i = 0; i < 8; ++i) {
            int s = sgrp * 8 + i;
            float x  = v[i];
            float ax = fabsf(x);
            float e  = __builtin_amdgcn_exp2f(-ax * LOG2E);
            float sp = fmaxf(x, 0.0f) + __builtin_amdgcn_logf(1.0f + e) * LN2;
            v[i] = sp * smask[s];
            lmax = fmaxf(lmax, v[i]);
        }
        redbuf[sgrp * TG + gA] = lmax;
        __syncthreads();

        // ---- B1: running max + rescale factor per grid col
        if (tid < TG) {
            float cm = redbuf[tid];
#pragma unroll
            for (int k = 1; k < NGRP; ++k) cm = fmaxf(cm, redbuf[k * TG + tid]);
            float mold = mS[tid];
            float mnew = fmaxf(mold, cm);
            alphaS[tid] = __builtin_amdgcn_exp2f((mold - mnew) * LOG2E);
            mS[tid] = mnew;
        }
        __syncthreads();

        // ---- B2: p = exp(v-m) -> f16 hi+lo, A-frag layout; sum fp32 p
        {
            float m  = mS[gA];
            float ps = 0.0f;
            f16x8 fh, fl;
#pragma unroll
            for (int i = 0; i < 8; ++i) {
                float p = __builtin_amdgcn_exp2f((v[i] - m) * LOG2E);
                _Float16 h = (_Float16)p;
                fh[i] = h;
                fl[i] = (_Float16)(p - (float)h);
                ps += p;
            }
            const int idx = ((sgrp >> 2) << 6) + (((sgrp & 3) << 4) | gA);
            fragAh[idx] = fh;
            fragAl[idx] = fl;
            redbuf[sgrp * TG + gA] = ps;
        }
        __syncthreads();

        // ---- B3: denominator update (runs alongside phase C)
        if (tid < TG) {
            float t = 0.0f;
#pragma unroll
            for (int k = 0; k < NGRP; ++k) t += redbuf[k * TG + tid];
            lS[tid] = lS[tid] * alphaS[tid] + t;
        }

        // ---- Phase C: rescale accumulators (rows m = (lane>>4)*4+reg), MFMA
        {
            const f32x4 al = *(const f32x4*)&alphaS[(lane >> 4) * 4];
#pragma unroll
            for (int t = 0; t < 4; ++t) acc[t] = acc[t] * al;

            const int srow = s0 + ((lane >> 4) * 8);
            const int dbase = wv * 64 + (lane & 15);
#pragma unroll
            for (int kc = 0; kc < 4; ++kc) {
                f16x8 ah = fragAh[(kc << 6) + lane];
                f16x8 al16 = fragAl[(kc << 6) + lane];
#pragma unroll
                for (int t = 0; t < 4; ++t) {
                    const size_t off = (size_t)(dbase + t * 16) * NSTA + srow + kc * 32;
                    f16x8 bh = *(const f16x8*)(fhb + off);
                    f16x8 bl = *(const f16x8*)(flb + off);
                    acc[t] = __builtin_amdgcn_mfma_f32_16x16x32_f16(ah, bh, acc[t], 0, 0, 0);
                    acc[t] = __builtin_amdgcn_mfma_f32_16x16x32_f16(ah, bl, acc[t], 0, 0, 0);
                    acc[t] = __builtin_amdgcn_mfma_f32_16x16x32_f16(al16, bh, acc[t], 0, 0, 0);
                }
            }
        }
    }
    __syncthreads();   // lS, mS final

    // ---- epilogue: write UNNORMALIZED partial acc + (m,l); comb_kernel merges halves
    {
        float* dst = half ? acc1 : out;
        const int m0 = (lane >> 4) * 4;
        const size_t gbase = (size_t)lat * NLON + lon0 + m0;
#pragma unroll
        for (int t = 0; t < 4; ++t) {
            const int d = wv * 64 + t * 16 + (lane & 15);
            *reinterpret_cast<f32x4*>(dst + ((size_t)(b * HID + d)) * NG + gbase) = acc[t];
        }
        if (tid < TG)
            ml[((half << 1) + b) * NG + lat * NLON + lon0 + tid] = make_float2(mS[tid], lS[tid]);
    }
}

// ---- Combine kernel: out = (acc0*e^{m0-M} + acc1*e^{m1-M}) / (l0*e^{m0-M} + l1*e^{m1-M})
__global__ __launch_bounds__(256)
void comb_kernel(float* __restrict__ out, const float* __restrict__ acc1,
                 const float2* __restrict__ ml) {
    const int x    = blockIdx.x;          // 1024 = b(2) * lat(64) * dseg(8)
    const int b    = x >> 9;
    const int lat  = (x >> 3) & 63;
    const int dseg = x & 7;               // 32 d each
    const int lon  = threadIdx.x & 127;
    const int dsub = threadIdx.x >> 7;    // 0..1
    const int g    = lat * NLON + lon;

    const float2 p0 = ml[b * NG + g];
    const float2 p1 = ml[(2 + b) * NG + g];
    const float M  = fmaxf(p0.x, p1.x);
    float s0 = __builtin_amdgcn_exp2f((p0.x - M) * LOG2E);
    float s1 = __builtin_amdgcn_exp2f((p1.x - M) * LOG2E);
    const float rl = 1.0f / fmaf(p0.y, s0, p1.y * s1);
    s0 *= rl; s1 *= rl;

#pragma unroll 4
    for (int k = 0; k < 16; ++k) {
        const int d = dseg * 32 + dsub + k * 2;
        const size_t o = ((size_t)(b * HID + d)) * NG + g;
        out[o] = fmaf(out[o], s0, acc1[o] * s1);
    }
}

extern "C" void kernel_launch(void* const* d_in, const int* in_sizes, int n_in,
                              void* d_out, int out_size, void* d_ws, size_t ws_size,
                              hipStream_t stream) {
    const float* feats  = (const float*)d_in[0];
    const float* coords = (const float*)d_in[1];
    const float* maskp  = (const float*)d_in[2];
    const float* W1     = (const float*)d_in[3];
    const float* b1     = (const float*)d_in[4];
    const float* W2     = (const float*)d_in[5];
    const float* b2     = (const float*)d_in[6];
    float* out          = (float*)d_out;

    // workspace map:
    //   fhi  [2][256][1024] f16 : 1 MB
    //   flo  [2][256][1024] f16 : 1 MB
    //   acc1 [2][256][8192] f32 : 16 MB   (half-1 partial; half-0 goes to d_out)
    //   ml   [2][2][8192] float2: 256 KB
    _Float16* fhi = (_Float16*)d_ws;
    _Float16* flo = fhi + (size_t)2 * HID * NSTA;
    float*  acc1 = (float*)((char*)d_ws + (size_t)2 * 1048576);
    float2* ml   = (float2*)((char*)d_ws + (size_t)2 * 1048576 + (size_t)2 * HID * NG * 4);

    hipLaunchKernelGGL(cvt_kernel, dim3(256), dim3(256), 0, stream, feats, fhi, flo);
    hipLaunchKernelGGL(s2g_kernel, dim3(2048), dim3(256), 0, stream,
                       coords, maskp, W1, b1, W2, b2, fhi, flo, out, acc1, ml);
    hipLaunchKernelGGL(comb_kernel, dim3(1024), dim3(256), 0, stream, out, acc1, ml);
}